// Round 8
// baseline (95.023 us; speedup 1.0000x reference)
//
#include <hip/hip_runtime.h>

#define NB 16
#define IN_CH 64
#define OUT_CH 256
#define NH 48
#define NW 48
#define NPIX (NH * NW)                 // 2304
#define ROW_STRIDE 52                  // dwords per staged halo row
#define CH_STRIDE (4 * ROW_STRIDE)     // 208 dwords per channel (4 halo rows)
#define LDS_DW (IN_CH * CH_STRIDE)     // 13312 dwords = 53,248 B -> 3 blocks/CU
#define NITEMS (IN_CH * 4 * 26)        // 6656 float2 staging items
#define META_F4 9                      // per o: [0..1]=8 int offsets, [2..8]=7 node weights

__constant__ float c_gate[16 * 4] = {
    0.f, 0.f, 0.f, 0.f,
    0.f, 0.f, 0.f, 1.f,
    0.f, 1.f, 0.f, -1.f,
    0.f, 1.f, 0.f, 0.f,
    0.f, 0.f, 1.f, -1.f,
    0.f, 0.f, 1.f, 0.f,
    0.f, 1.f, 1.f, -2.f,
    0.f, 1.f, 1.f, -1.f,
    1.f, -1.f, -1.f, 1.f,
    1.f, -1.f, -1.f, 2.f,
    1.f, 0.f, -1.f, 0.f,
    1.f, 0.f, -1.f, 1.f,
    1.f, -1.f, 0.f, 0.f,
    1.f, -1.f, 0.f, 1.f,
    1.f, 0.f, 0.f, -1.f,
    1.f, 0.f, 0.f, 0.f
};

// meta[o][36 dw]: 0..7 = int LDS offsets (c*CH_STRIDE + di*ROW_STRIDE + dj),
//                8..35 = 7 nodes x 4 floats (softmax(logits) @ GATE_COEFF)
__global__ __launch_bounds__(256) void prep_kernel(
    const float* __restrict__ logits,
    const int*   __restrict__ leaf_idx,
    float*       __restrict__ meta)
{
    int t = blockIdx.x * 256 + threadIdx.x;
    if (t < OUT_CH * 8) {
        int idx = leaf_idx[t];
        int c  = idx / 9;
        int k  = idx - c * 9;
        int di = k / 3;
        int dj = k - di * 3;
        reinterpret_cast<int*>(meta)[(t >> 3) * 36 + (t & 7)] =
            c * CH_STRIDE + di * ROW_STRIDE + dj;
    } else {
        int t2 = t - OUT_CH * 8;
        if (t2 >= OUT_CH * 7) return;
        int o = t2 / 7;
        int n = t2 - o * 7;
        const float* lg = logits + (size_t)t2 * 16;

        float m = lg[0];
#pragma unroll
        for (int g = 1; g < 16; ++g) m = fmaxf(m, lg[g]);
        float e16[16];
        float s = 0.f;
#pragma unroll
        for (int g = 0; g < 16; ++g) { e16[g] = expf(lg[g] - m); s += e16[g]; }
        float inv = 1.f / s;

        float w0 = 0.f, w1 = 0.f, w2 = 0.f, w3 = 0.f;
#pragma unroll
        for (int g = 0; g < 16; ++g) {
            float p = e16[g] * inv;
            w0 += p * c_gate[g * 4 + 0];
            w1 += p * c_gate[g * 4 + 1];
            w2 += p * c_gate[g * 4 + 2];
            w3 += p * c_gate[g * 4 + 3];
        }
        float* mw = meta + o * 36 + 8 + n * 4;
        mw[0] = w0; mw[1] = w1; mw[2] = w2; mw[3] = w3;
    }
}

// soft-logic tree eval: 8 leaf values + 7 float4 node weights -> scalar
__device__ __forceinline__ float tree_eval(
    const float* v,
    const float4& W0, const float4& W1, const float4& W2, const float4& W3,
    const float4& W4, const float4& W5, const float4& W6)
{
    float t0 = fmaf(v[1], fmaf(W0.w, v[0], W0.z), fmaf(W0.y, v[0], W0.x));
    float t1 = fmaf(v[3], fmaf(W1.w, v[2], W1.z), fmaf(W1.y, v[2], W1.x));
    float t2 = fmaf(v[5], fmaf(W2.w, v[4], W2.z), fmaf(W2.y, v[4], W2.x));
    float t3 = fmaf(v[7], fmaf(W3.w, v[6], W3.z), fmaf(W3.y, v[6], W3.x));
    float u0 = fmaf(t1, fmaf(W4.w, t0, W4.z), fmaf(W4.y, t0, W4.x));
    float u1 = fmaf(t3, fmaf(W5.w, t2, W5.z), fmaf(W5.y, t2, W5.x));
    return fmaf(u1, fmaf(W6.w, u0, W6.z), fmaf(W6.y, u0, W6.x));
}

// grid = (24 bands, 2 o-halves, 16 batches), block = 512 (8 waves), 3 blocks/CU.
// Wave = 4 o-groups x 16 lanes; lane covers 6 px (3 col-slots x 2 rows) of the
// 2-row band. Per leaf, all 6 px share ONE base LDS address with constant
// dword deltas {0,16,32,52,68,84} -> adjacent pairs merge into ds_read2_b32
// (halves DS-pipe instruction count vs b32 gathers).
__global__ __launch_bounds__(512, 6) void ltc_kernel(
    const float*  __restrict__ x,     // [B][64][48][48]
    const float4* __restrict__ meta,  // [OUT_CH][9]
    float*        __restrict__ out)   // [B][OUT_CH][48][48]
{
    __shared__ float lds[LDS_DW];

    const int band  = blockIdx.x;     // 0..23
    const int ohalf = blockIdx.y;     // 0..1
    const int b     = blockIdx.z;     // 0..15
    const int r0    = band * 2;
    const int tid   = threadIdx.x;

    // ---- stage 4-row halo as float2: layout [c][4][52], image col g at lds col g+2 ----
    const float* xb = x + (size_t)b * IN_CH * NPIX;
    for (int it = tid; it < NITEMS; it += 512) {
        int c   = it / 104;                 // 104 = 4 rows * 26 pairs
        int rem = it - c * 104;
        int r4  = rem / 26;
        int p   = rem - r4 * 26;            // pair: lds cols 2p, 2p+1
        int gr  = r0 - 1 + r4;
        float2 v = make_float2(0.f, 0.f);
        if (p > 0 && p < 25 && (unsigned)gr < NH)
            v = *reinterpret_cast<const float2*>(xb + (c * NH + gr) * NW + (2 * p - 2));
        *reinterpret_cast<float2*>(&lds[c * CH_STRIDE + r4 * ROW_STRIDE + 2 * p]) = v;
    }
    __syncthreads();

    const int lane = tid & 63;
    const int wid  = tid >> 6;               // 0..7
    const int q    = lane >> 4;              // o-group 0..3
    const int pxg  = lane & 15;              // col slot 0..15
    const int o0   = ohalf * 128 + ((wid << 2) | q) * 4;   // first of 4 channels
    const int cbase = pxg + 1;               // base col offset (incl. +2 shift, -1 conv)

    const float4* mptr  = meta + (size_t)o0 * META_F4;
    float*        pbase = out + ((size_t)b * OUT_CH + o0) * NPIX + r0 * NW + pxg;

#pragma unroll 1
    for (int i = 0; i < 4; ++i) {
        float4 M0 = mptr[0], M1 = mptr[1];
        float4 W0 = mptr[2], W1 = mptr[3], W2 = mptr[4];
        float4 W3 = mptr[5], W4 = mptr[6], W5 = mptr[7], W6 = mptr[8];

        int vb[8];
        vb[0] = __float_as_int(M0.x) + cbase;
        vb[1] = __float_as_int(M0.y) + cbase;
        vb[2] = __float_as_int(M0.z) + cbase;
        vb[3] = __float_as_int(M0.w) + cbase;
        vb[4] = __float_as_int(M1.x) + cbase;
        vb[5] = __float_as_int(M1.y) + cbase;
        vb[6] = __float_as_int(M1.z) + cbase;
        vb[7] = __float_as_int(M1.w) + cbase;

        float va[8], vc[8];
        float y0, y1;

        // pair 0: (row0, c) & (row0, c+16)  -> ds_read2_b32 offsets {0,16}
#pragma unroll
        for (int j = 0; j < 8; ++j) { va[j] = lds[vb[j]]; vc[j] = lds[vb[j] + 16]; }
        y0 = tree_eval(va, W0, W1, W2, W3, W4, W5, W6);
        y1 = tree_eval(vc, W0, W1, W2, W3, W4, W5, W6);
        pbase[0]  = y0; pbase[16] = y1;

        // pair 1: (row1, c) & (row1, c+16)  -> offsets {52,68}
#pragma unroll
        for (int j = 0; j < 8; ++j) { va[j] = lds[vb[j] + 52]; vc[j] = lds[vb[j] + 68]; }
        y0 = tree_eval(va, W0, W1, W2, W3, W4, W5, W6);
        y1 = tree_eval(vc, W0, W1, W2, W3, W4, W5, W6);
        pbase[48] = y0; pbase[64] = y1;

        // pair 2: (row0, c+32) & (row1, c+32) -> offsets {32,84}
#pragma unroll
        for (int j = 0; j < 8; ++j) { va[j] = lds[vb[j] + 32]; vc[j] = lds[vb[j] + 84]; }
        y0 = tree_eval(va, W0, W1, W2, W3, W4, W5, W6);
        y1 = tree_eval(vc, W0, W1, W2, W3, W4, W5, W6);
        pbase[32] = y0; pbase[80] = y1;

        mptr  += META_F4;
        pbase += NPIX;
    }
}

extern "C" void kernel_launch(void* const* d_in, const int* in_sizes, int n_in,
                              void* d_out, int out_size, void* d_ws, size_t ws_size,
                              hipStream_t stream) {
    const float* x        = (const float*)d_in[0];
    const float* logits   = (const float*)d_in[1];
    const int*   leaf_idx = (const int*)d_in[2];
    float*       out      = (float*)d_out;
    float*       meta     = (float*)d_ws;    // 256*36 dwords = 36,864 B

    prep_kernel<<<15, 256, 0, stream>>>(logits, leaf_idx, meta);

    dim3 grid(24, 2, NB);
    ltc_kernel<<<grid, 512, 0, stream>>>(x, (const float4*)meta, out);
}

// Round 9
// 33.734 us; speedup vs baseline: 2.8169x; 2.8169x over previous
//
#include <hip/hip_runtime.h>

#define NB 16
#define IN_CH 64
#define OUT_CH 256
#define NH 48
#define NW 48
#define NPIX (NH * NW)                 // 2304
#define ROW_STRIDE 52                  // dwords per staged halo row
#define CH_STRIDE (4 * ROW_STRIDE)     // 208 dwords per channel (4 halo rows)
#define LDS_DW (IN_CH * CH_STRIDE)     // 13312 dwords = 53,248 B -> 3 blocks/CU
#define NITEMS (IN_CH * 4 * 26)        // 6656 float2 staging items
#define META_F4 9                      // per o: [0..1]=8 int offsets, [2..8]=7 node weights

__constant__ float c_gate[16 * 4] = {
    0.f, 0.f, 0.f, 0.f,
    0.f, 0.f, 0.f, 1.f,
    0.f, 1.f, 0.f, -1.f,
    0.f, 1.f, 0.f, 0.f,
    0.f, 0.f, 1.f, -1.f,
    0.f, 0.f, 1.f, 0.f,
    0.f, 1.f, 1.f, -2.f,
    0.f, 1.f, 1.f, -1.f,
    1.f, -1.f, -1.f, 1.f,
    1.f, -1.f, -1.f, 2.f,
    1.f, 0.f, -1.f, 0.f,
    1.f, 0.f, -1.f, 1.f,
    1.f, -1.f, 0.f, 0.f,
    1.f, -1.f, 0.f, 1.f,
    1.f, 0.f, 0.f, -1.f,
    1.f, 0.f, 0.f, 0.f
};

// meta[o][36 dw]: 0..7 = int LDS offsets (c*CH_STRIDE + di*ROW_STRIDE + dj),
//                8..35 = 7 nodes x 4 floats (softmax(logits) @ GATE_COEFF)
__global__ __launch_bounds__(256) void prep_kernel(
    const float* __restrict__ logits,
    const int*   __restrict__ leaf_idx,
    float*       __restrict__ meta)
{
    int t = blockIdx.x * 256 + threadIdx.x;
    if (t < OUT_CH * 8) {
        int idx = leaf_idx[t];
        int c  = idx / 9;
        int k  = idx - c * 9;
        int di = k / 3;
        int dj = k - di * 3;
        reinterpret_cast<int*>(meta)[(t >> 3) * 36 + (t & 7)] =
            c * CH_STRIDE + di * ROW_STRIDE + dj;
    } else {
        int t2 = t - OUT_CH * 8;
        if (t2 >= OUT_CH * 7) return;
        int o = t2 / 7;
        int n = t2 - o * 7;
        const float* lg = logits + (size_t)t2 * 16;

        float m = lg[0];
#pragma unroll
        for (int g = 1; g < 16; ++g) m = fmaxf(m, lg[g]);
        float e16[16];
        float s = 0.f;
#pragma unroll
        for (int g = 0; g < 16; ++g) { e16[g] = expf(lg[g] - m); s += e16[g]; }
        float inv = 1.f / s;

        float w0 = 0.f, w1 = 0.f, w2 = 0.f, w3 = 0.f;
#pragma unroll
        for (int g = 0; g < 16; ++g) {
            float p = e16[g] * inv;
            w0 += p * c_gate[g * 4 + 0];
            w1 += p * c_gate[g * 4 + 1];
            w2 += p * c_gate[g * 4 + 2];
            w3 += p * c_gate[g * 4 + 3];
        }
        float* mw = meta + o * 36 + 8 + n * 4;
        mw[0] = w0; mw[1] = w1; mw[2] = w2; mw[3] = w3;
    }
}

// grid = (24 bands, 2 o-halves, 16 batches), block = 512 (8 waves), 3 blocks/CU.
// Wave = 2 o-groups x 32 px lanes (stores stay 32-lane contiguous = 128B).
// Offsets for iteration i+1 are prefetched (ping-ponged in regs) so the
// address-forming L2 loads never sit on the critical path.
__global__ __launch_bounds__(512, 6) void ltc_kernel(
    const float*  __restrict__ x,     // [B][64][48][48]
    const float4* __restrict__ meta,  // [OUT_CH][9] (+1 record pad readable)
    float*        __restrict__ out)   // [B][OUT_CH][48][48]
{
    __shared__ float lds[LDS_DW];

    const int band  = blockIdx.x;     // 0..23
    const int ohalf = blockIdx.y;     // 0..1
    const int b     = blockIdx.z;     // 0..15
    const int r0    = band * 2;
    const int tid   = threadIdx.x;

    // ---- stage 4-row halo as float2: layout [c][4][52], image col g at lds col g+2 ----
    const float* xb = x + (size_t)b * IN_CH * NPIX;
    for (int it = tid; it < NITEMS; it += 512) {
        int c   = it / 104;                 // 104 = 4 rows * 26 pairs
        int rem = it - c * 104;
        int r4  = rem / 26;
        int p   = rem - r4 * 26;            // pair: lds cols 2p, 2p+1
        int gr  = r0 - 1 + r4;
        float2 v = make_float2(0.f, 0.f);
        if (p > 0 && p < 25 && (unsigned)gr < NH)
            v = *reinterpret_cast<const float2*>(xb + (c * NH + gr) * NW + (2 * p - 2));
        *reinterpret_cast<float2*>(&lds[c * CH_STRIDE + r4 * ROW_STRIDE + 2 * p]) = v;
    }
    __syncthreads();

    const int lane = tid & 63;
    const int wid  = tid >> 6;               // 0..7
    const int og   = lane >> 5;              // 0..1
    const int pxg  = lane & 31;              // 0..31
    const int o0   = ohalf * 128 + ((wid << 1) | og) * 8;  // first of 8 channels

    // per-lane pixel bases for 3 px-groups (96 px = 2 rows x 48)
    int bases[3], opx[3];
#pragma unroll
    for (int g = 0; g < 3; ++g) {
        int px = g * 32 + pxg;               // 0..95
        int rr = (px >= 48) ? 1 : 0;
        int cc = px - rr * 48;
        bases[g] = rr * ROW_STRIDE + cc + 1; // gather col = cc + dj - 1 (+2 shift)
        opx[g]   = (r0 + rr) * NW + cc;
    }

    const float4* mptr  = meta + (size_t)o0 * META_F4;
    float*        pbase = out + ((size_t)b * OUT_CH + o0) * NPIX;

    // prologue: offsets for i=0
    float4 F0 = mptr[0], F1 = mptr[1];

#pragma unroll 1
    for (int i = 0; i < 8; ++i) {
        // prefetch next iteration's offsets (last iter reads 1 pad record; never used)
        float4 N0 = mptr[META_F4 + 0];
        float4 N1 = mptr[META_F4 + 1];

        // weights for current channel (latency overlaps the ds_read phase)
        float4 W0 = mptr[2], W1 = mptr[3], W2 = mptr[4];
        float4 W3 = mptr[5], W4 = mptr[6], W5 = mptr[7], W6 = mptr[8];

        const int off0 = __float_as_int(F0.x);
        const int off1 = __float_as_int(F0.y);
        const int off2 = __float_as_int(F0.z);
        const int off3 = __float_as_int(F0.w);
        const int off4 = __float_as_int(F1.x);
        const int off5 = __float_as_int(F1.y);
        const int off6 = __float_as_int(F1.z);
        const int off7 = __float_as_int(F1.w);

#pragma unroll
        for (int g = 0; g < 3; ++g) {
            const int bg = bases[g];
            float v0 = lds[off0 + bg];
            float v1 = lds[off1 + bg];
            float v2 = lds[off2 + bg];
            float v3 = lds[off3 + bg];
            float v4 = lds[off4 + bg];
            float v5 = lds[off5 + bg];
            float v6 = lds[off6 + bg];
            float v7 = lds[off7 + bg];
            float t0 = fmaf(v1, fmaf(W0.w, v0, W0.z), fmaf(W0.y, v0, W0.x));
            float t1 = fmaf(v3, fmaf(W1.w, v2, W1.z), fmaf(W1.y, v2, W1.x));
            float t2 = fmaf(v5, fmaf(W2.w, v4, W2.z), fmaf(W2.y, v4, W2.x));
            float t3 = fmaf(v7, fmaf(W3.w, v6, W3.z), fmaf(W3.y, v6, W3.x));
            float u0 = fmaf(t1, fmaf(W4.w, t0, W4.z), fmaf(W4.y, t0, W4.x));
            float u1 = fmaf(t3, fmaf(W5.w, t2, W5.z), fmaf(W5.y, t2, W5.x));
            float y  = fmaf(u1, fmaf(W6.w, u0, W6.z), fmaf(W6.y, u0, W6.x));
            pbase[opx[g]] = y;
        }

        F0 = N0; F1 = N1;
        mptr  += META_F4;
        pbase += NPIX;
    }
}

extern "C" void kernel_launch(void* const* d_in, const int* in_sizes, int n_in,
                              void* d_out, int out_size, void* d_ws, size_t ws_size,
                              hipStream_t stream) {
    const float* x        = (const float*)d_in[0];
    const float* logits   = (const float*)d_in[1];
    const int*   leaf_idx = (const int*)d_in[2];
    float*       out      = (float*)d_out;
    float*       meta     = (float*)d_ws;    // 256*36 dwords = 36,864 B (+pad in ws)

    prep_kernel<<<15, 256, 0, stream>>>(logits, leaf_idx, meta);

    dim3 grid(24, 2, NB);
    ltc_kernel<<<grid, 512, 0, stream>>>(x, (const float4*)meta, out);
}